// Round 4
// baseline (417.889 us; speedup 1.0000x reference)
//
#include <hip/hip_runtime.h>
#include <hip/hip_bf16.h>
#include <hip/hip_fp16.h>

typedef __bf16 bf16;
typedef bf16 bf16x2 __attribute__((ext_vector_type(2)));
typedef bf16 bf16x4 __attribute__((ext_vector_type(4)));
typedef bf16 bf16x8 __attribute__((ext_vector_type(8)));
typedef float f32x2 __attribute__((ext_vector_type(2)));
typedef float f32x4 __attribute__((ext_vector_type(4)));

__device__ __forceinline__ void gload_lds16(const void* g, void* l) {
  __builtin_amdgcn_global_load_lds((__attribute__((address_space(1))) void*)g,
                                   (__attribute__((address_space(3))) void*)l,
                                   16, 0, 0);
}

__device__ __forceinline__ f32x2 fma2(f32x2 a, f32x2 b, f32x2 c) {
  return __builtin_elementwise_fma(a, b, c);   // -> v_pk_fma_f32
}

__device__ __forceinline__ f32x2 cvt2(unsigned int u) {
  __half2 h = *(__half2*)&u;
  float2 f = __half22float2(h);
  f32x2 r = {f.x, f.y};
  return r;
}

// ---------------- prep kernels ----------------

__global__ void cast_f32_to_bf16(const float* __restrict__ in, bf16* __restrict__ out, int n4) {
  int i = blockIdx.x * blockDim.x + threadIdx.x;
  if (i >= n4) return;
  float4 v = ((const float4*)in)[i];
  bf16x4 o = {(bf16)v.x, (bf16)v.y, (bf16)v.z, (bf16)v.w};
  ((bf16x4*)out)[i] = o;
}

__global__ void cast_w3(const float* __restrict__ uw, const float* __restrict__ vw,
                        const float* __restrict__ ow,
                        bf16* __restrict__ wuv, bf16* __restrict__ owb) {
  int t = blockIdx.x * 256 + threadIdx.x;
  int r = t >> 17;
  int i = t & 131071;
  const float* src = (r == 0) ? uw : (r == 1) ? vw : ow;
  bf16* dst = (r == 2) ? owb : (wuv + (r == 1) * 524288);
  float4 v = ((const float4*)src)[i];
  bf16x4 o = {(bf16)v.x, (bf16)v.y, (bf16)v.z, (bf16)v.w};
  ((bf16x4*)dst)[i] = o;
}

__global__ void concat_bias(const float* __restrict__ ub, const float* __restrict__ vb,
                            float* __restrict__ buv) {
  int i = blockIdx.x * blockDim.x + threadIdx.x;
  if (i < 1024) { buv[i] = ub[i]; buv[1024 + i] = vb[i]; }
}

// Toeplitz table, f16 channel-pair packed: Tkp[h][lag+63][cpair] (u32 = 2 f16).
__global__ void build_tkp(const float* __restrict__ zero, const float* __restrict__ pa,
                          const float* __restrict__ pb, const float* __restrict__ na,
                          const float* __restrict__ nb, unsigned int* __restrict__ Tkp,
                          float scale) {
  int idx = blockIdx.x * blockDim.x + threadIdx.x;
  if (idx >= 8 * 127 * 64) return;
  int cp = idx & 63;
  int lagIdx = (idx >> 6) % 127;
  int h = idx / (64 * 127);
  int lag = lagIdx - 63;
  float t0, t1;
  if (lag == 0) {
    t0 = zero[h * 128 + 2 * cp];
    t1 = zero[h * 128 + 2 * cp + 1];
  } else {
    int k = lag > 0 ? lag : -lag;
    const float* A  = lag > 0 ? pa : na;
    const float* Bm = lag > 0 ? pb : nb;
    float pos_f = (float)(k - 1) * (15.0f / 62.0f);
    int lo = (int)floorf(pos_f);
    int hi = min(lo + 1, 15);
    float w = pos_f - (float)lo;
    float s0 = 0.f, s1 = 0.f;
    for (int r = 0; r < 32; ++r) {
      float c = (1.f - w) * A[(h * 16 + lo) * 32 + r] + w * A[(h * 16 + hi) * 32 + r];
      s0 += c * Bm[(h * 32 + r) * 128 + 2 * cp];
      s1 += c * Bm[(h * 32 + r) * 128 + 2 * cp + 1];
    }
    float dec = powf(0.999f, (float)k);
    t0 = s0 * dec;
    t1 = s1 * dec;
  }
  __half2 hv = __floats2half2_rn(t0 * scale, t1 * scale);
  Tkp[idx] = *(unsigned int*)&hv;
}

// ------------- fused GEMM(u,v) + toep1-on-v (128x128 tile, B^T, XCD swizzle) -------------
// v-tile (bc>=1024) = 2 image rows x 1 head: silu(v) -> LDS, 64-tap W-mix in-block,
// write tmid. u-tile: silu -> u. T1 window read from L2-resident global table.

#define VP 132   // vls row stride (bf16 elems)

__global__ __launch_bounds__(256, 3)
void gemm_uvt(const bf16* __restrict__ A, const bf16* __restrict__ B,
              const float* __restrict__ bias, const unsigned int* __restrict__ Tkp1,
              bf16* __restrict__ out_u, bf16* __restrict__ tmid) {
  __shared__ __align__(16) char smem[2 * 64 * VP * 2];   // 33792 B; aliases As|Bs then vls
  bf16* As = (bf16*)smem;                 // 128*32
  bf16* Bs = (bf16*)(smem + 8192);        // 128*32
  bf16* vls = (bf16*)smem;                // [2][64][VP]
  const int K = 512;
  const int tid  = threadIdx.x;
  const int lane = tid & 63;
  const int cpx  = gridDim.x >> 3;
  const int swz  = (blockIdx.x & 7) * cpx + (blockIdx.x >> 3);
  const int br   = (swz >> 4) << 7;       // nbn = 16
  const int bc   = (swz & 15) << 7;
  const int wub  = __builtin_amdgcn_readfirstlane(tid & 192);

  f32x4 acc[4][4] = {};

  auto stage = [&](int k0) {
#pragma unroll
    for (int r = 0; r < 2; ++r) {
      const int flat = r * 256 + tid;
      const int row  = flat >> 2;
      const int kc   = (flat & 3) << 3;
      gload_lds16(A + ((size_t)(br + row) * K + k0 + kc),
                  (char*)As + (size_t)(r * 256 + wub) * 16);
      gload_lds16(B + ((size_t)(bc + row) * K + k0 + kc),
                  (char*)Bs + (size_t)(r * 256 + wub) * 16);
    }
  };

  const int l15 = lane & 15;
  const int lk  = (lane >> 4) << 3;
  const int wr  = ((tid >> 7) & 1) << 6;
  const int wc  = ((tid >> 6) & 1) << 6;

  auto compute = [&]() {
    bf16x8 af[4], bfr[4];
#pragma unroll
    for (int m = 0; m < 4; ++m)
      af[m] = *(const bf16x8*)&As[(wr + m * 16 + l15) * 32 + lk];
#pragma unroll
    for (int n = 0; n < 4; ++n)
      bfr[n] = *(const bf16x8*)&Bs[(wc + n * 16 + l15) * 32 + lk];
#pragma unroll
    for (int m = 0; m < 4; ++m)
#pragma unroll
      for (int n = 0; n < 4; ++n)
        acc[m][n] = __builtin_amdgcn_mfma_f32_16x16x32_bf16(af[m], bfr[n], acc[m][n], 0, 0, 0);
  };

  stage(0);
  __syncthreads();
  for (int k0 = 32; k0 < K; k0 += 32) {
    compute();
    __syncthreads();
    stage(k0);
    __syncthreads();
  }
  compute();
  __syncthreads();   // all waves done reading As/Bs before any vls overwrite

  const int lr4 = (lane >> 4) << 2;
  if (bc < 1024) {
    // ---- u path: silu -> u ----
#pragma unroll
    for (int m = 0; m < 4; ++m) {
#pragma unroll
      for (int n = 0; n < 4; ++n) {
        const int col = bc + wc + n * 16 + l15;
        const float bv = bias[col];
#pragma unroll
        for (int r = 0; r < 4; ++r) {
          const int row = br + wr + m * 16 + lr4 + r;
          float xv = acc[m][n][r] + bv;
          float s  = xv / (1.f + __expf(-xv));
          out_u[(size_t)row * 1024 + col] = (bf16)s;
        }
      }
    }
  } else {
    // ---- v path: silu -> vls, in-block toep1 (W-mix), -> tmid ----
    const int head = (bc - 1024) >> 7;
#pragma unroll
    for (int m = 0; m < 4; ++m) {
#pragma unroll
      for (int n = 0; n < 4; ++n) {
        const int col = wc + n * 16 + l15;            // 0..127 (channel in head)
        const float bv = bias[bc + col];
#pragma unroll
        for (int r = 0; r < 4; ++r) {
          const int rin = wr + m * 16 + lr4 + r;      // 0..127
          float xv = acc[m][n][r] + bv;
          float s  = xv / (1.f + __expf(-xv));
          vls[rin * VP + col] = (bf16)s;              // rin = ir*64 + j
        }
      }
    }
    __syncthreads();

    const unsigned int* tg = Tkp1 + head * 8128;
    const int i0 = (tid >> 6) << 4;                   // wave's 16-output base
    for (int ir = 0; ir < 2; ++ir) {
      f32x2 acc2[16] = {};
      for (int jb = 0; jb < 4; ++jb) {
        f32x2 t[31];
        const int tb = (i0 - 16 * jb + 48) * 64 + lane;
#pragma unroll
        for (int s = 0; s < 31; ++s) t[s] = cvt2(tg[tb + s * 64]);
#pragma unroll
        for (int jj = 0; jj < 16; ++jj) {
          unsigned int vu =
            *(const unsigned int*)&vls[(ir * 64 + jb * 16 + jj) * VP + (lane << 1)];
          f32x2 v2;
          v2.x = __uint_as_float(vu << 16);
          v2.y = __uint_as_float(vu & 0xFFFF0000u);
#pragma unroll
          for (int ii = 0; ii < 16; ++ii)
            acc2[ii] = fma2(t[ii - jj + 15], v2, acc2[ii]);
        }
      }
      const size_t obase = (size_t)(br + ir * 64) * 1024 + (bc - 1024) + (lane << 1);
#pragma unroll
      for (int ii = 0; ii < 16; ++ii) {
        bf16x2 o2 = {(bf16)acc2[ii].x, (bf16)acc2[ii].y};
        *(bf16x2*)(tmid + obase + (size_t)(i0 + ii) * 1024) = o2;
      }
    }
  }
}

// ---------------- plain GEMM for output projection (f32 out) ----------------

__global__ __launch_bounds__(256)
void gemm_bt1(const bf16* __restrict__ A, const bf16* __restrict__ B,
              const float* __restrict__ bias, float* __restrict__ out_f,
              int M, int N, int K) {
  __shared__ bf16 As[128 * 32];
  __shared__ bf16 Bs[128 * 32];
  const int tid  = threadIdx.x;
  const int lane = tid & 63;
  const int nbn  = N >> 7;
  const int cpx  = gridDim.x >> 3;
  const int swz  = (blockIdx.x & 7) * cpx + (blockIdx.x >> 3);
  const int br   = (swz / nbn) << 7;
  const int bc   = (swz % nbn) << 7;
  const int wub  = __builtin_amdgcn_readfirstlane(tid & 192);

  f32x4 acc[4][4] = {};

  auto stage = [&](int k0) {
#pragma unroll
    for (int r = 0; r < 2; ++r) {
      const int flat = r * 256 + tid;
      const int row  = flat >> 2;
      const int kc   = (flat & 3) << 3;
      gload_lds16(A + ((size_t)(br + row) * K + k0 + kc),
                  (char*)As + (size_t)(r * 256 + wub) * 16);
      gload_lds16(B + ((size_t)(bc + row) * K + k0 + kc),
                  (char*)Bs + (size_t)(r * 256 + wub) * 16);
    }
  };

  const int l15 = lane & 15;
  const int lk  = (lane >> 4) << 3;
  const int wr  = ((tid >> 7) & 1) << 6;
  const int wc  = ((tid >> 6) & 1) << 6;

  auto compute = [&]() {
    bf16x8 af[4], bfr[4];
#pragma unroll
    for (int m = 0; m < 4; ++m)
      af[m] = *(const bf16x8*)&As[(wr + m * 16 + l15) * 32 + lk];
#pragma unroll
    for (int n = 0; n < 4; ++n)
      bfr[n] = *(const bf16x8*)&Bs[(wc + n * 16 + l15) * 32 + lk];
#pragma unroll
    for (int m = 0; m < 4; ++m)
#pragma unroll
      for (int n = 0; n < 4; ++n)
        acc[m][n] = __builtin_amdgcn_mfma_f32_16x16x32_bf16(af[m], bfr[n], acc[m][n], 0, 0, 0);
  };

  stage(0);
  __syncthreads();
  for (int k0 = 32; k0 < K; k0 += 32) {
    compute();
    __syncthreads();
    stage(k0);
    __syncthreads();
  }
  compute();

  const int lr4 = (lane >> 4) << 2;
#pragma unroll
  for (int m = 0; m < 4; ++m) {
#pragma unroll
    for (int n = 0; n < 4; ++n) {
      const int col = bc + wc + n * 16 + l15;
      const float bv = bias[col];
#pragma unroll
      for (int r = 0; r < 4; ++r) {
        const int row = br + wr + m * 16 + lr4 + r;
        out_f[(size_t)row * N + col] = acc[m][n][r] + bv;
      }
    }
  }
}

// ---------------- Toeplitz pass (standalone, H-mix + gate fuse) -------------

template<int FUSE>
__global__ __launch_bounds__(256, 2)
void toep_pass(const bf16* __restrict__ in, const unsigned int* __restrict__ Tkp,
               const bf16* __restrict__ ufuse, bf16* __restrict__ out,
               int stride_j, int stride_row) {
  __shared__ unsigned int tkl[8192];
  __shared__ bf16 vbuf[64 * 132];
  const int tid    = threadIdx.x;
  const int rowIdx = blockIdx.x >> 3;
  const int head   = blockIdx.x & 7;
  const size_t base = (size_t)(rowIdx >> 6) * 4194304
                    + (size_t)(rowIdx & 63) * stride_row + head * 128;

  {
    const unsigned int* tg = Tkp + head * 8128;
    const int wub = __builtin_amdgcn_readfirstlane(tid & 192);
#pragma unroll
    for (int it = 0; it < 8; ++it) {
      const int flat = it * 256 + tid;
      gload_lds16(tg + flat * 4, (char*)tkl + (size_t)(it * 256 + wub) * 16);
    }
  }
#pragma unroll
  for (int it = 0; it < 2; ++it) {
    int c  = it * 256 + tid;
    int j  = c >> 3;
    int cg = c & 7;
    const bf16* p = in + base + (size_t)j * stride_j + cg * 16;
    bf16x8 a0 = *(const bf16x8*)p;
    bf16x8 a1 = *(const bf16x8*)(p + 8);
    *(bf16x8*)&vbuf[j * 132 + cg * 16]     = a0;
    *(bf16x8*)&vbuf[j * 132 + cg * 16 + 8] = a1;
  }
  __syncthreads();

  const int lane = tid & 63;
  const int i0   = (tid >> 6) << 4;
  f32x2 acc[16] = {};

  for (int jb = 0; jb < 4; ++jb) {
    f32x2 t[31];
    const int tbase = (i0 - 16 * jb + 48) * 64 + lane;
#pragma unroll
    for (int s = 0; s < 31; ++s) t[s] = cvt2(tkl[tbase + s * 64]);
#pragma unroll
    for (int jj = 0; jj < 16; ++jj) {
      unsigned int vu = *(const unsigned int*)&vbuf[(jb * 16 + jj) * 132 + (lane << 1)];
      f32x2 v2;
      v2.x = __uint_as_float(vu << 16);
      v2.y = __uint_as_float(vu & 0xFFFF0000u);
#pragma unroll
      for (int ii = 0; ii < 16; ++ii)
        acc[ii] = fma2(t[ii - jj + 15], v2, acc[ii]);
    }
  }

  const int d0 = lane << 1;
#pragma unroll
  for (int ii = 0; ii < 16; ++ii) {
    const size_t oidx = base + (size_t)(i0 + ii) * stride_j + d0;
    float a0 = acc[ii].x, a1 = acc[ii].y;
    if (FUSE) {
      bf16x2 uu = *(const bf16x2*)(ufuse + oidx);
      a0 *= (float)uu[0];
      a1 *= (float)uu[1];
    }
    bf16x2 o2 = {(bf16)a0, (bf16)a1};
    *(bf16x2*)(out + oidx) = o2;
  }
}

// ---------------- launch ----------------

extern "C" void kernel_launch(void* const* d_in, const int* in_sizes, int n_in,
                              void* d_out, int out_size, void* d_ws, size_t ws_size,
                              hipStream_t stream) {
  const float* x    = (const float*)d_in[0];
  const float* u_w  = (const float*)d_in[1];
  const float* u_b  = (const float*)d_in[2];
  const float* v_w  = (const float*)d_in[3];
  const float* v_b  = (const float*)d_in[4];
  const float* o_w  = (const float*)d_in[5];
  const float* o_b  = (const float*)d_in[6];
  const float* t1z  = (const float*)d_in[7];
  const float* t1pa = (const float*)d_in[8];
  const float* t1pb = (const float*)d_in[9];
  const float* t1na = (const float*)d_in[10];
  const float* t1nb = (const float*)d_in[11];
  const float* t2z  = (const float*)d_in[12];
  const float* t2pa = (const float*)d_in[13];
  const float* t2pb = (const float*)d_in[14];
  const float* t2na = (const float*)d_in[15];
  const float* t2nb = (const float*)d_in[16];

  char* ws = (char*)d_ws;
  size_t off = 0;
  auto alloc = [&](size_t bytes) {
    char* p = ws + off;
    off += (bytes + 255) & ~(size_t)255;
    return p;
  };
  bf16*  xb   = (bf16*)alloc(32768ull * 512 * 2);
  bf16*  wuv  = (bf16*)alloc(2048ull * 512 * 2);
  bf16*  owb  = (bf16*)alloc(512ull * 1024 * 2);
  float* buv  = (float*)alloc(2048ull * 4);
  unsigned int* Tkp1 = (unsigned int*)alloc(8ull * 127 * 64 * 4 + 256);
  unsigned int* Tkp2 = (unsigned int*)alloc(8ull * 127 * 64 * 4 + 256);
  bf16*  u    = (bf16*)alloc(32768ull * 1024 * 2);
  bf16*  tmid = (bf16*)alloc(32768ull * 1024 * 2);
  bf16*  g    = (bf16*)alloc(32768ull * 1024 * 2);

  cast_f32_to_bf16<<<16384, 256, 0, stream>>>(x, xb, 16777216 / 4);
  cast_w3<<<1536, 256, 0, stream>>>(u_w, v_w, o_w, wuv, owb);
  concat_bias<<<4, 256, 0, stream>>>(u_b, v_b, buv);
  build_tkp<<<254, 256, 0, stream>>>(t1z, t1pa, t1pb, t1na, t1nb, Tkp1, 1.0f);
  build_tkp<<<254, 256, 0, stream>>>(t2z, t2pa, t2pb, t2na, t2nb, Tkp2, 2.0f);

  // u = silu(xU); tmid = toep1_W(silu(xV))   [fused]
  gemm_uvt<<<4096, 256, 0, stream>>>(xb, wuv, buv, Tkp1, u, tmid);
  // g = u * toep2_H(tmid) (x2 folded in Tkp2)
  toep_pass<1><<<4096, 256, 0, stream>>>(tmid, Tkp2, u, g, 65536, 1024);
  // out = g @ o_w^T + o_b
  gemm_bt1<<<1024, 256, 0, stream>>>(g, owb, o_b, (float*)d_out, 32768, 512, 1024);
}

// Round 5
// 347.022 us; speedup vs baseline: 1.2042x; 1.2042x over previous
//
#include <hip/hip_runtime.h>
#include <hip/hip_bf16.h>
#include <hip/hip_fp16.h>

typedef __bf16 bf16;
typedef bf16 bf16x2 __attribute__((ext_vector_type(2)));
typedef bf16 bf16x4 __attribute__((ext_vector_type(4)));
typedef bf16 bf16x8 __attribute__((ext_vector_type(8)));
typedef float f32x2 __attribute__((ext_vector_type(2)));
typedef float f32x4 __attribute__((ext_vector_type(4)));

__device__ __forceinline__ void gload_lds16(const void* g, void* l) {
  __builtin_amdgcn_global_load_lds((__attribute__((address_space(1))) void*)g,
                                   (__attribute__((address_space(3))) void*)l,
                                   16, 0, 0);
}

__device__ __forceinline__ f32x2 fma2(f32x2 a, f32x2 b, f32x2 c) {
  return __builtin_elementwise_fma(a, b, c);   // -> v_pk_fma_f32
}

// ---------------- prep kernels ----------------

__global__ void cast_f32_to_bf16(const float* __restrict__ in, bf16* __restrict__ out, int n4) {
  int i = blockIdx.x * blockDim.x + threadIdx.x;
  if (i >= n4) return;
  float4 v = ((const float4*)in)[i];
  bf16x4 o = {(bf16)v.x, (bf16)v.y, (bf16)v.z, (bf16)v.w};
  ((bf16x4*)out)[i] = o;
}

__global__ void cast_w3(const float* __restrict__ uw, const float* __restrict__ vw,
                        const float* __restrict__ ow,
                        bf16* __restrict__ wuv, bf16* __restrict__ owb) {
  int t = blockIdx.x * 256 + threadIdx.x;
  int r = t >> 17;
  int i = t & 131071;
  const float* src = (r == 0) ? uw : (r == 1) ? vw : ow;
  bf16* dst = (r == 2) ? owb : (wuv + (r == 1) * 524288);
  float4 v = ((const float4*)src)[i];
  bf16x4 o = {(bf16)v.x, (bf16)v.y, (bf16)v.z, (bf16)v.w};
  ((bf16x4*)dst)[i] = o;
}

__global__ void concat_bias(const float* __restrict__ ub, const float* __restrict__ vb,
                            float* __restrict__ buv) {
  int i = blockIdx.x * blockDim.x + threadIdx.x;
  if (i < 1024) { buv[i] = ub[i]; buv[1024 + i] = vb[i]; }
}

// Toeplitz table, f32: Tkf[h][lag+63][d], d = 0..127. L2-resident (520 KB).
__global__ void build_tkf(const float* __restrict__ zero, const float* __restrict__ pa,
                          const float* __restrict__ pb, const float* __restrict__ na,
                          const float* __restrict__ nb, float* __restrict__ Tkf,
                          float scale) {
  int idx = blockIdx.x * blockDim.x + threadIdx.x;
  if (idx >= 8 * 127 * 128) return;
  int d = idx & 127;
  int lagIdx = (idx >> 7) % 127;
  int h = idx / (128 * 127);
  int lag = lagIdx - 63;
  float val;
  if (lag == 0) {
    val = zero[h * 128 + d];
  } else {
    int k = lag > 0 ? lag : -lag;
    const float* A  = lag > 0 ? pa : na;
    const float* Bm = lag > 0 ? pb : nb;
    float pos_f = (float)(k - 1) * (15.0f / 62.0f);
    int lo = (int)floorf(pos_f);
    int hi = min(lo + 1, 15);
    float w = pos_f - (float)lo;
    float s = 0.f;
    for (int r = 0; r < 32; ++r) {
      float c = (1.f - w) * A[(h * 16 + lo) * 32 + r] + w * A[(h * 16 + hi) * 32 + r];
      s += c * Bm[(h * 32 + r) * 128 + d];
    }
    val = s * powf(0.999f, (float)k);
  }
  Tkf[idx] = val * scale;
}

// ---------------- GEMM (m97-style 128x128, B^T input, XCD swizzle) ----------------
// MODE 0: bias+silu, bf16 out split into u (cols<1024) / v (cols>=1024), stride 1024
// MODE 1: bias only, f32 out, stride N

template<int MODE>
__global__ __launch_bounds__(256)
void gemm_bt(const bf16* __restrict__ A, const bf16* __restrict__ B,
             const float* __restrict__ bias,
             bf16* __restrict__ out_u, bf16* __restrict__ out_v,
             float* __restrict__ out_f,
             int M, int N, int K) {
  __shared__ bf16 As[128 * 32];
  __shared__ bf16 Bs[128 * 32];
  const int tid  = threadIdx.x;
  const int lane = tid & 63;
  const int nbn  = N >> 7;
  const int cpx  = gridDim.x >> 3;
  const int swz  = (blockIdx.x & 7) * cpx + (blockIdx.x >> 3);
  const int br   = (swz / nbn) << 7;
  const int bc   = (swz % nbn) << 7;
  const int wub  = __builtin_amdgcn_readfirstlane(tid & 192);

  f32x4 acc[4][4] = {};

  auto stage = [&](int k0) {
#pragma unroll
    for (int r = 0; r < 2; ++r) {
      const int flat = r * 256 + tid;
      const int row  = flat >> 2;
      const int kc   = (flat & 3) << 3;
      gload_lds16(A + ((size_t)(br + row) * K + k0 + kc),
                  (char*)As + (size_t)(r * 256 + wub) * 16);
      gload_lds16(B + ((size_t)(bc + row) * K + k0 + kc),
                  (char*)Bs + (size_t)(r * 256 + wub) * 16);
    }
  };

  const int l15 = lane & 15;
  const int lk  = (lane >> 4) << 3;
  const int wr  = ((tid >> 7) & 1) << 6;
  const int wc  = ((tid >> 6) & 1) << 6;

  auto compute = [&]() {
    bf16x8 af[4], bfr[4];
#pragma unroll
    for (int m = 0; m < 4; ++m)
      af[m] = *(const bf16x8*)&As[(wr + m * 16 + l15) * 32 + lk];
#pragma unroll
    for (int n = 0; n < 4; ++n)
      bfr[n] = *(const bf16x8*)&Bs[(wc + n * 16 + l15) * 32 + lk];
#pragma unroll
    for (int m = 0; m < 4; ++m)
#pragma unroll
      for (int n = 0; n < 4; ++n)
        acc[m][n] = __builtin_amdgcn_mfma_f32_16x16x32_bf16(af[m], bfr[n], acc[m][n], 0, 0, 0);
  };

  stage(0);
  __syncthreads();
  for (int k0 = 32; k0 < K; k0 += 32) {
    compute();
    __syncthreads();
    stage(k0);
    __syncthreads();
  }
  compute();

  const int lr4 = (lane >> 4) << 2;
  if (MODE == 0) {
    const bool isU = (bc < 1024);
    bf16* outp = isU ? out_u : out_v;
#pragma unroll
    for (int m = 0; m < 4; ++m) {
#pragma unroll
      for (int n = 0; n < 4; ++n) {
        const int col  = bc + wc + n * 16 + l15;
        const int ocol = (bc & 1023) + wc + n * 16 + l15;
        const float bv = bias[col];
#pragma unroll
        for (int r = 0; r < 4; ++r) {
          const int row = br + wr + m * 16 + lr4 + r;
          float xv = acc[m][n][r] + bv;
          float s  = xv / (1.f + __expf(-xv));
          outp[(size_t)row * 1024 + ocol] = (bf16)s;
        }
      }
    }
  } else {
#pragma unroll
    for (int m = 0; m < 4; ++m) {
#pragma unroll
      for (int n = 0; n < 4; ++n) {
        const int col  = bc + wc + n * 16 + l15;
        const float bv = bias[col];
#pragma unroll
        for (int r = 0; r < 4; ++r) {
          const int row = br + wr + m * 16 + lr4 + r;
          out_f[(size_t)row * N + col] = acc[m][n][r] + bv;
        }
      }
    }
  }
}

// ---------------- Toeplitz pass v4: lean high-occupancy conv -------------
// Block: one image row (64 pos) x one head (128 ch). 4 waves; wave w owns
// i in [16w,16w+16), lane owns channel pair. v staged in LDS as f32 (cvt once);
// T window read from L2-resident f32 global table (no LDS copy, no cvt).
// Inner step: 1 ds_read_b64 + 16 v_pk_fma_f32. LDS 33.3KB -> 4 blk/CU,
// VGPR ~112 under the (256,4) cap of 128.

#define VROW 130   // f32 row stride (128 + 2 pad)

template<int FUSE>
__global__ __launch_bounds__(256, 4)
void toep_pass(const bf16* __restrict__ in, const float* __restrict__ Tkf,
               const bf16* __restrict__ ufuse, bf16* __restrict__ out,
               int stride_j, int stride_row) {
  __shared__ float vbuf[64 * VROW];
  const int tid    = threadIdx.x;
  const int rowIdx = blockIdx.x >> 3;
  const int head   = blockIdx.x & 7;
  const size_t base = (size_t)(rowIdx >> 6) * 4194304
                    + (size_t)(rowIdx & 63) * stride_row + head * 128;

  // stage v row (64 j x 128 ch) bf16 -> f32
#pragma unroll
  for (int it = 0; it < 2; ++it) {
    int c  = it * 256 + tid;
    int j  = c >> 3;
    int cg = c & 7;
    const bf16* p = in + base + (size_t)j * stride_j + cg * 16;
    bf16x8 a0 = *(const bf16x8*)p;
    bf16x8 a1 = *(const bf16x8*)(p + 8);
    f32x4 f0 = {(float)a0[0], (float)a0[1], (float)a0[2], (float)a0[3]};
    f32x4 f1 = {(float)a0[4], (float)a0[5], (float)a0[6], (float)a0[7]};
    f32x4 f2 = {(float)a1[0], (float)a1[1], (float)a1[2], (float)a1[3]};
    f32x4 f3 = {(float)a1[4], (float)a1[5], (float)a1[6], (float)a1[7]};
    float* dst = &vbuf[j * VROW + cg * 16];
    *(f32x4*)(dst)      = f0;
    *(f32x4*)(dst + 4)  = f1;
    *(f32x4*)(dst + 8)  = f2;
    *(f32x4*)(dst + 12) = f3;
  }
  __syncthreads();

  const int lane = tid & 63;
  const int i0   = (tid >> 6) << 4;
  const float* tg = Tkf + head * 127 * 128 + (lane << 1);
  f32x2 acc[16] = {};

  for (int jb = 0; jb < 4; ++jb) {      // not unrolled: t[] regs reused
    // T window: lagIdx = i0 - 16*jb + 48 + s, s = 0..30
    f32x2 t[31];
    const float* tb = tg + (i0 - 16 * jb + 48) * 128;
#pragma unroll
    for (int s = 0; s < 31; ++s) t[s] = *(const f32x2*)(tb + s * 128);
#pragma unroll
    for (int jj = 0; jj < 16; ++jj) {
      f32x2 v2 = *(const f32x2*)&vbuf[(jb * 16 + jj) * VROW + (lane << 1)];
#pragma unroll
      for (int ii = 0; ii < 16; ++ii)
        acc[ii] = fma2(t[ii - jj + 15], v2, acc[ii]);
    }
  }

  const int d0 = lane << 1;
#pragma unroll
  for (int ii = 0; ii < 16; ++ii) {
    const size_t oidx = base + (size_t)(i0 + ii) * stride_j + d0;
    float a0 = acc[ii].x, a1 = acc[ii].y;
    if (FUSE) {
      bf16x2 uu = *(const bf16x2*)(ufuse + oidx);
      a0 *= (float)uu[0];
      a1 *= (float)uu[1];
    }
    bf16x2 o2 = {(bf16)a0, (bf16)a1};
    *(bf16x2*)(out + oidx) = o2;
  }
}

// ---------------- launch ----------------

extern "C" void kernel_launch(void* const* d_in, const int* in_sizes, int n_in,
                              void* d_out, int out_size, void* d_ws, size_t ws_size,
                              hipStream_t stream) {
  const float* x    = (const float*)d_in[0];
  const float* u_w  = (const float*)d_in[1];
  const float* u_b  = (const float*)d_in[2];
  const float* v_w  = (const float*)d_in[3];
  const float* v_b  = (const float*)d_in[4];
  const float* o_w  = (const float*)d_in[5];
  const float* o_b  = (const float*)d_in[6];
  const float* t1z  = (const float*)d_in[7];
  const float* t1pa = (const float*)d_in[8];
  const float* t1pb = (const float*)d_in[9];
  const float* t1na = (const float*)d_in[10];
  const float* t1nb = (const float*)d_in[11];
  const float* t2z  = (const float*)d_in[12];
  const float* t2pa = (const float*)d_in[13];
  const float* t2pb = (const float*)d_in[14];
  const float* t2na = (const float*)d_in[15];
  const float* t2nb = (const float*)d_in[16];

  char* ws = (char*)d_ws;
  size_t off = 0;
  auto alloc = [&](size_t bytes) {
    char* p = ws + off;
    off += (bytes + 255) & ~(size_t)255;
    return p;
  };
  bf16*  xb   = (bf16*)alloc(32768ull * 512 * 2);
  bf16*  wuv  = (bf16*)alloc(2048ull * 512 * 2);
  bf16*  owb  = (bf16*)alloc(512ull * 1024 * 2);
  float* buv  = (float*)alloc(2048ull * 4);
  float* Tkf1 = (float*)alloc(8ull * 127 * 128 * 4);
  float* Tkf2 = (float*)alloc(8ull * 127 * 128 * 4);
  bf16*  u    = (bf16*)alloc(32768ull * 1024 * 2);
  bf16*  v    = (bf16*)alloc(32768ull * 1024 * 2);
  bf16*  tmid = (bf16*)alloc(32768ull * 1024 * 2);
  bf16*  g    = v;   // v dead after toep1; reuse for gate output

  cast_f32_to_bf16<<<16384, 256, 0, stream>>>(x, xb, 16777216 / 4);
  cast_w3<<<1536, 256, 0, stream>>>(u_w, v_w, o_w, wuv, owb);
  concat_bias<<<4, 256, 0, stream>>>(u_b, v_b, buv);
  build_tkf<<<508, 256, 0, stream>>>(t1z, t1pa, t1pb, t1na, t1nb, Tkf1, 1.0f);
  build_tkf<<<508, 256, 0, stream>>>(t2z, t2pa, t2pb, t2na, t2nb, Tkf2, 2.0f);  // x2 folded

  // u,v = silu(x @ [Wu;Wv]^T + b)
  gemm_bt<0><<<4096, 256, 0, stream>>>(xb, wuv, buv, u, v, nullptr, 32768, 2048, 512);
  // W-axis mix (t1)
  toep_pass<0><<<4096, 256, 0, stream>>>(v, Tkf1, nullptr, tmid, 1024, 65536);
  // H-axis mix (t2), gate fused (x2 in Tkf2)
  toep_pass<1><<<4096, 256, 0, stream>>>(tmid, Tkf2, u, g, 65536, 1024);
  // out = g @ o_w^T + o_b
  gemm_bt<1><<<1024, 256, 0, stream>>>(g, owb, o_b, nullptr, nullptr, (float*)d_out,
                                       32768, 512, 1024);
}

// Round 6
// 318.045 us; speedup vs baseline: 1.3139x; 1.0911x over previous
//
#include <hip/hip_runtime.h>
#include <hip/hip_bf16.h>
#include <hip/hip_fp16.h>

typedef __bf16 bf16;
typedef bf16 bf16x2 __attribute__((ext_vector_type(2)));
typedef bf16 bf16x4 __attribute__((ext_vector_type(4)));
typedef bf16 bf16x8 __attribute__((ext_vector_type(8)));
typedef float f32x2 __attribute__((ext_vector_type(2)));
typedef float f32x4 __attribute__((ext_vector_type(4)));

__device__ __forceinline__ void gload_lds16(const void* g, void* l) {
  __builtin_amdgcn_global_load_lds((__attribute__((address_space(1))) void*)g,
                                   (__attribute__((address_space(3))) void*)l,
                                   16, 0, 0);
}

__device__ __forceinline__ f32x2 fma2(f32x2 a, f32x2 b, f32x2 c) {
  return __builtin_elementwise_fma(a, b, c);   // -> v_pk_fma_f32
}

// ---------------- prep kernels ----------------

__global__ void cast_f32_to_bf16(const float* __restrict__ in, bf16* __restrict__ out, int n4) {
  int i = blockIdx.x * blockDim.x + threadIdx.x;
  if (i >= n4) return;
  float4 v = ((const float4*)in)[i];
  bf16x4 o = {(bf16)v.x, (bf16)v.y, (bf16)v.z, (bf16)v.w};
  ((bf16x4*)out)[i] = o;
}

__global__ void cast_w3(const float* __restrict__ uw, const float* __restrict__ vw,
                        const float* __restrict__ ow,
                        bf16* __restrict__ wuv, bf16* __restrict__ owb) {
  int t = blockIdx.x * 256 + threadIdx.x;
  int r = t >> 17;
  int i = t & 131071;
  const float* src = (r == 0) ? uw : (r == 1) ? vw : ow;
  bf16* dst = (r == 2) ? owb : (wuv + (r == 1) * 524288);
  float4 v = ((const float4*)src)[i];
  bf16x4 o = {(bf16)v.x, (bf16)v.y, (bf16)v.z, (bf16)v.w};
  ((bf16x4*)dst)[i] = o;
}

__global__ void concat_bias(const float* __restrict__ ub, const float* __restrict__ vb,
                            float* __restrict__ buv) {
  int i = blockIdx.x * blockDim.x + threadIdx.x;
  if (i < 1024) { buv[i] = ub[i]; buv[1024 + i] = vb[i]; }
}

// Toeplitz table, f32: Tkf[h][lag+63][d], d = 0..127. L2-resident (520 KB).
__global__ void build_tkf(const float* __restrict__ zero, const float* __restrict__ pa,
                          const float* __restrict__ pb, const float* __restrict__ na,
                          const float* __restrict__ nb, float* __restrict__ Tkf,
                          float scale) {
  int idx = blockIdx.x * blockDim.x + threadIdx.x;
  if (idx >= 8 * 127 * 128) return;
  int d = idx & 127;
  int lagIdx = (idx >> 7) % 127;
  int h = idx / (128 * 127);
  int lag = lagIdx - 63;
  float val;
  if (lag == 0) {
    val = zero[h * 128 + d];
  } else {
    int k = lag > 0 ? lag : -lag;
    const float* A  = lag > 0 ? pa : na;
    const float* Bm = lag > 0 ? pb : nb;
    float pos_f = (float)(k - 1) * (15.0f / 62.0f);
    int lo = (int)floorf(pos_f);
    int hi = min(lo + 1, 15);
    float w = pos_f - (float)lo;
    float s = 0.f;
    for (int r = 0; r < 32; ++r) {
      float c = (1.f - w) * A[(h * 16 + lo) * 32 + r] + w * A[(h * 16 + hi) * 32 + r];
      s += c * Bm[(h * 32 + r) * 128 + d];
    }
    val = s * powf(0.999f, (float)k);
  }
  Tkf[idx] = val * scale;
}

// ---------------- GEMM (m97-style 128x128, B^T input, XCD swizzle) ----------------
// MODE 0: bias+silu, bf16 out split into u (cols<1024) / v (cols>=1024), stride 1024
// MODE 1: bias only, f32 out, stride N

template<int MODE>
__global__ __launch_bounds__(256)
void gemm_bt(const bf16* __restrict__ A, const bf16* __restrict__ B,
             const float* __restrict__ bias,
             bf16* __restrict__ out_u, bf16* __restrict__ out_v,
             float* __restrict__ out_f,
             int M, int N, int K) {
  __shared__ bf16 As[128 * 32];
  __shared__ bf16 Bs[128 * 32];
  const int tid  = threadIdx.x;
  const int lane = tid & 63;
  const int nbn  = N >> 7;
  const int cpx  = gridDim.x >> 3;
  const int swz  = (blockIdx.x & 7) * cpx + (blockIdx.x >> 3);
  const int br   = (swz / nbn) << 7;
  const int bc   = (swz % nbn) << 7;
  const int wub  = __builtin_amdgcn_readfirstlane(tid & 192);

  f32x4 acc[4][4] = {};

  auto stage = [&](int k0) {
#pragma unroll
    for (int r = 0; r < 2; ++r) {
      const int flat = r * 256 + tid;
      const int row  = flat >> 2;
      const int kc   = (flat & 3) << 3;
      gload_lds16(A + ((size_t)(br + row) * K + k0 + kc),
                  (char*)As + (size_t)(r * 256 + wub) * 16);
      gload_lds16(B + ((size_t)(bc + row) * K + k0 + kc),
                  (char*)Bs + (size_t)(r * 256 + wub) * 16);
    }
  };

  const int l15 = lane & 15;
  const int lk  = (lane >> 4) << 3;
  const int wr  = ((tid >> 7) & 1) << 6;
  const int wc  = ((tid >> 6) & 1) << 6;

  auto compute = [&]() {
    bf16x8 af[4], bfr[4];
#pragma unroll
    for (int m = 0; m < 4; ++m)
      af[m] = *(const bf16x8*)&As[(wr + m * 16 + l15) * 32 + lk];
#pragma unroll
    for (int n = 0; n < 4; ++n)
      bfr[n] = *(const bf16x8*)&Bs[(wc + n * 16 + l15) * 32 + lk];
#pragma unroll
    for (int m = 0; m < 4; ++m)
#pragma unroll
      for (int n = 0; n < 4; ++n)
        acc[m][n] = __builtin_amdgcn_mfma_f32_16x16x32_bf16(af[m], bfr[n], acc[m][n], 0, 0, 0);
  };

  stage(0);
  __syncthreads();
  for (int k0 = 32; k0 < K; k0 += 32) {
    compute();
    __syncthreads();
    stage(k0);
    __syncthreads();
  }
  compute();

  const int lr4 = (lane >> 4) << 2;
  if (MODE == 0) {
    const bool isU = (bc < 1024);
    bf16* outp = isU ? out_u : out_v;
#pragma unroll
    for (int m = 0; m < 4; ++m) {
#pragma unroll
      for (int n = 0; n < 4; ++n) {
        const int col  = bc + wc + n * 16 + l15;
        const int ocol = (bc & 1023) + wc + n * 16 + l15;
        const float bv = bias[col];
#pragma unroll
        for (int r = 0; r < 4; ++r) {
          const int row = br + wr + m * 16 + lr4 + r;
          float xv = acc[m][n][r] + bv;
          float s  = xv / (1.f + __expf(-xv));
          outp[(size_t)row * 1024 + ocol] = (bf16)s;
        }
      }
    }
  } else {
#pragma unroll
    for (int m = 0; m < 4; ++m) {
#pragma unroll
      for (int n = 0; n < 4; ++n) {
        const int col  = bc + wc + n * 16 + l15;
        const float bv = bias[col];
#pragma unroll
        for (int r = 0; r < 4; ++r) {
          const int row = br + wr + m * 16 + lr4 + r;
          out_f[(size_t)row * N + col] = acc[m][n][r] + bv;
        }
      }
    }
  }
}

// ---------------- Toeplitz pass v5: register-shift window + prefetch -------------
// Block: one image row (64 pos) x one head (128 ch). 4 waves; wave w owns
// i in [16w,16w+16), lane owns channel pair. v staged in LDS as f32.
// T window in registers; consecutive jb windows overlap by 15 -> only 16 fresh
// loads per jb, issued BEFORE the 256-FMA block so L2 latency hides under FMA.
// jb fully unrolled -> all t[]/p16[] indices static (registers, no scratch).

#define VROW 130   // f32 row stride (128 + 2 pad)

template<int FUSE>
__global__ __launch_bounds__(256, 3)
void toep_pass(const bf16* __restrict__ in, const float* __restrict__ Tkf,
               const bf16* __restrict__ ufuse, bf16* __restrict__ out,
               int stride_j, int stride_row) {
  __shared__ float vbuf[64 * VROW];
  const int tid    = threadIdx.x;
  const int lane   = tid & 63;
  const int rowIdx = blockIdx.x >> 3;
  const int head   = blockIdx.x & 7;
  const size_t base = (size_t)(rowIdx >> 6) * 4194304
                    + (size_t)(rowIdx & 63) * stride_row + head * 128;

  const int i0 = (tid >> 6) << 4;
  const float* tg = Tkf + head * 127 * 128 + (lane << 1);

  // issue jb=0 T window early: lagIdx = i0+48+s  (latency overlaps staging+barrier)
  f32x2 t[31];
#pragma unroll
  for (int s = 0; s < 31; ++s)
    t[s] = *(const f32x2*)(tg + (i0 + 48 + s) * 128);

  // stage v row (64 j x 128 ch) bf16 -> f32
#pragma unroll
  for (int it = 0; it < 2; ++it) {
    int c  = it * 256 + tid;
    int j  = c >> 3;
    int cg = c & 7;
    const bf16* p = in + base + (size_t)j * stride_j + cg * 16;
    bf16x8 a0 = *(const bf16x8*)p;
    bf16x8 a1 = *(const bf16x8*)(p + 8);
    f32x4 f0 = {(float)a0[0], (float)a0[1], (float)a0[2], (float)a0[3]};
    f32x4 f1 = {(float)a0[4], (float)a0[5], (float)a0[6], (float)a0[7]};
    f32x4 f2 = {(float)a1[0], (float)a1[1], (float)a1[2], (float)a1[3]};
    f32x4 f3 = {(float)a1[4], (float)a1[5], (float)a1[6], (float)a1[7]};
    float* dst = &vbuf[j * VROW + cg * 16];
    *(f32x4*)(dst)      = f0;
    *(f32x4*)(dst + 4)  = f1;
    *(f32x4*)(dst + 8)  = f2;
    *(f32x4*)(dst + 12) = f3;
  }
  __syncthreads();

  f32x2 acc[16] = {};
#pragma unroll
  for (int jb = 0; jb < 4; ++jb) {
    // prefetch the 16 fresh lags of window jb+1 (consumed after this FMA block)
    f32x2 p16[16];
    if (jb < 3) {
#pragma unroll
      for (int s = 0; s < 16; ++s)
        p16[s] = *(const f32x2*)(tg + (i0 - 16 * (jb + 1) + 48 + s) * 128);
    }
#pragma unroll
    for (int jj = 0; jj < 16; ++jj) {
      f32x2 v2 = *(const f32x2*)&vbuf[(jb * 16 + jj) * VROW + (lane << 1)];
#pragma unroll
      for (int ii = 0; ii < 16; ++ii)
        acc[ii] = fma2(t[ii - jj + 15], v2, acc[ii]);
    }
    if (jb < 3) {
      // shift window: new t[s] = old t[s-16] (s>=16), fresh p16[s] (s<16)
#pragma unroll
      for (int s = 30; s >= 16; --s) t[s] = t[s - 16];
#pragma unroll
      for (int s = 0; s < 16; ++s) t[s] = p16[s];
    }
  }

  const int d0 = lane << 1;
#pragma unroll
  for (int ii = 0; ii < 16; ++ii) {
    const size_t oidx = base + (size_t)(i0 + ii) * stride_j + d0;
    float a0 = acc[ii].x, a1 = acc[ii].y;
    if (FUSE) {
      bf16x2 uu = *(const bf16x2*)(ufuse + oidx);
      a0 *= (float)uu[0];
      a1 *= (float)uu[1];
    }
    bf16x2 o2 = {(bf16)a0, (bf16)a1};
    *(bf16x2*)(out + oidx) = o2;
  }
}

// ---------------- launch ----------------

extern "C" void kernel_launch(void* const* d_in, const int* in_sizes, int n_in,
                              void* d_out, int out_size, void* d_ws, size_t ws_size,
                              hipStream_t stream) {
  const float* x    = (const float*)d_in[0];
  const float* u_w  = (const float*)d_in[1];
  const float* u_b  = (const float*)d_in[2];
  const float* v_w  = (const float*)d_in[3];
  const float* v_b  = (const float*)d_in[4];
  const float* o_w  = (const float*)d_in[5];
  const float* o_b  = (const float*)d_in[6];
  const float* t1z  = (const float*)d_in[7];
  const float* t1pa = (const float*)d_in[8];
  const float* t1pb = (const float*)d_in[9];
  const float* t1na = (const float*)d_in[10];
  const float* t1nb = (const float*)d_in[11];
  const float* t2z  = (const float*)d_in[12];
  const float* t2pa = (const float*)d_in[13];
  const float* t2pb = (const float*)d_in[14];
  const float* t2na = (const float*)d_in[15];
  const float* t2nb = (const float*)d_in[16];

  char* ws = (char*)d_ws;
  size_t off = 0;
  auto alloc = [&](size_t bytes) {
    char* p = ws + off;
    off += (bytes + 255) & ~(size_t)255;
    return p;
  };
  bf16*  xb   = (bf16*)alloc(32768ull * 512 * 2);
  bf16*  wuv  = (bf16*)alloc(2048ull * 512 * 2);
  bf16*  owb  = (bf16*)alloc(512ull * 1024 * 2);
  float* buv  = (float*)alloc(2048ull * 4);
  float* Tkf1 = (float*)alloc(8ull * 127 * 128 * 4);
  float* Tkf2 = (float*)alloc(8ull * 127 * 128 * 4);
  bf16*  u    = (bf16*)alloc(32768ull * 1024 * 2);
  bf16*  v    = (bf16*)alloc(32768ull * 1024 * 2);
  bf16*  tmid = (bf16*)alloc(32768ull * 1024 * 2);
  bf16*  g    = v;   // v dead after toep1; reuse for gate output

  cast_f32_to_bf16<<<16384, 256, 0, stream>>>(x, xb, 16777216 / 4);
  cast_w3<<<1536, 256, 0, stream>>>(u_w, v_w, o_w, wuv, owb);
  concat_bias<<<4, 256, 0, stream>>>(u_b, v_b, buv);
  build_tkf<<<508, 256, 0, stream>>>(t1z, t1pa, t1pb, t1na, t1nb, Tkf1, 1.0f);
  build_tkf<<<508, 256, 0, stream>>>(t2z, t2pa, t2pb, t2na, t2nb, Tkf2, 2.0f);  // x2 folded

  // u,v = silu(x @ [Wu;Wv]^T + b)
  gemm_bt<0><<<4096, 256, 0, stream>>>(xb, wuv, buv, u, v, nullptr, 32768, 2048, 512);
  // W-axis mix (t1)
  toep_pass<0><<<4096, 256, 0, stream>>>(v, Tkf1, nullptr, tmid, 1024, 65536);
  // H-axis mix (t2), gate fused (x2 in Tkf2)
  toep_pass<1><<<4096, 256, 0, stream>>>(tmid, Tkf2, u, g, 65536, 1024);
  // out = g @ o_w^T + o_b
  gemm_bt<1><<<1024, 256, 0, stream>>>(g, owb, o_b, nullptr, nullptr, (float*)d_out,
                                       32768, 512, 1024);
}

// Round 7
// 303.311 us; speedup vs baseline: 1.3778x; 1.0486x over previous
//
#include <hip/hip_runtime.h>
#include <hip/hip_bf16.h>
#include <hip/hip_fp16.h>

typedef __bf16 bf16;
typedef bf16 bf16x2 __attribute__((ext_vector_type(2)));
typedef bf16 bf16x4 __attribute__((ext_vector_type(4)));
typedef bf16 bf16x8 __attribute__((ext_vector_type(8)));
typedef float f32x2 __attribute__((ext_vector_type(2)));
typedef float f32x4 __attribute__((ext_vector_type(4)));

__device__ __forceinline__ void gload_lds16(const void* g, void* l) {
  __builtin_amdgcn_global_load_lds((__attribute__((address_space(1))) void*)g,
                                   (__attribute__((address_space(3))) void*)l,
                                   16, 0, 0);
}

__device__ __forceinline__ f32x2 fma2(f32x2 a, f32x2 b, f32x2 c) {
  return __builtin_elementwise_fma(a, b, c);   // -> v_pk_fma_f32
}

// ---------------- prep kernels ----------------

__global__ void cast_f32_to_bf16(const float* __restrict__ in, bf16* __restrict__ out, int n4) {
  int i = blockIdx.x * blockDim.x + threadIdx.x;
  if (i >= n4) return;
  float4 v = ((const float4*)in)[i];
  bf16x4 o = {(bf16)v.x, (bf16)v.y, (bf16)v.z, (bf16)v.w};
  ((bf16x4*)out)[i] = o;
}

__global__ void cast_w3(const float* __restrict__ uw, const float* __restrict__ vw,
                        const float* __restrict__ ow,
                        bf16* __restrict__ wuv, bf16* __restrict__ owb) {
  int t = blockIdx.x * 256 + threadIdx.x;
  int r = t >> 17;
  int i = t & 131071;
  const float* src = (r == 0) ? uw : (r == 1) ? vw : ow;
  bf16* dst = (r == 2) ? owb : (wuv + (r == 1) * 524288);
  float4 v = ((const float4*)src)[i];
  bf16x4 o = {(bf16)v.x, (bf16)v.y, (bf16)v.z, (bf16)v.w};
  ((bf16x4*)dst)[i] = o;
}

__global__ void concat_bias(const float* __restrict__ ub, const float* __restrict__ vb,
                            float* __restrict__ buv) {
  int i = blockIdx.x * blockDim.x + threadIdx.x;
  if (i < 1024) { buv[i] = ub[i]; buv[1024 + i] = vb[i]; }
}

// Toeplitz table, f32: Tkf[h][lag+63][d], d = 0..127. L2-resident (520 KB).
__global__ void build_tkf(const float* __restrict__ zero, const float* __restrict__ pa,
                          const float* __restrict__ pb, const float* __restrict__ na,
                          const float* __restrict__ nb, float* __restrict__ Tkf,
                          float scale) {
  int idx = blockIdx.x * blockDim.x + threadIdx.x;
  if (idx >= 8 * 127 * 128) return;
  int d = idx & 127;
  int lagIdx = (idx >> 7) % 127;
  int h = idx / (128 * 127);
  int lag = lagIdx - 63;
  float val;
  if (lag == 0) {
    val = zero[h * 128 + d];
  } else {
    int k = lag > 0 ? lag : -lag;
    const float* A  = lag > 0 ? pa : na;
    const float* Bm = lag > 0 ? pb : nb;
    float pos_f = (float)(k - 1) * (15.0f / 62.0f);
    int lo = (int)floorf(pos_f);
    int hi = min(lo + 1, 15);
    float w = pos_f - (float)lo;
    float s = 0.f;
    for (int r = 0; r < 32; ++r) {
      float c = (1.f - w) * A[(h * 16 + lo) * 32 + r] + w * A[(h * 16 + hi) * 32 + r];
      s += c * Bm[(h * 32 + r) * 128 + d];
    }
    val = s * powf(0.999f, (float)k);
  }
  Tkf[idx] = val * scale;
}

// ------------- GEMM v2: 256x256 tile, BK=64, 8 waves, dbuf LDS + swizzle -------------
// T1 XCD swizzle; T2 LDS XOR-swizzle (byte ^ ((row&7)<<4)) with linear gload_lds dest
// and pre-swizzled global source; per-K-tile: issue next tile's 8 gloads EARLY, then
// 4 phases {ds_read frags, setprio, 16 MFMA, raw s_barrier}; one __syncthreads per
// K-tile (drains loads issued ~4 phases earlier -> stall hidden).
// MODE 0: bias+silu, bf16 out split u/v (stride 1024). MODE 1: bias, f32 out (stride N).

template<int MODE>
__global__ __launch_bounds__(512, 2)
void gemm8(const bf16* __restrict__ A, const bf16* __restrict__ Bm,
           const float* __restrict__ bias,
           bf16* __restrict__ out_u, bf16* __restrict__ out_v,
           float* __restrict__ out_f, int M, int N, int K) {
  __shared__ __align__(16) char lds[131072];   // [2 buf][A 32KB | B 32KB]
  const int tid  = threadIdx.x;
  const int lane = tid & 63;
  const int l15  = lane & 15;
  const int lk16 = ((lane >> 4) & 3) << 4;     // frag k-offset, bytes
  const int w    = tid >> 6;
  const int wm   = (w >> 2) << 7;              // wave row base: 0 / 128
  const int wn   = (w & 3) << 6;               // wave col base: 0..192
  const int nbn  = N >> 8;
  const int cpx  = gridDim.x >> 3;
  const int swzb = (blockIdx.x & 7) * cpx + (blockIdx.x >> 3);
  const int br   = (swzb / nbn) << 8;
  const int bc   = (swzb % nbn) << 8;
  const int wub  = __builtin_amdgcn_readfirstlane(tid & 448);
  const int nkt  = K >> 6;

  f32x4 acc[8][4] = {};

  auto stage = [&](int kt, int b) {
    const int k0 = kt << 6;
    char* Al = lds + b * 65536;
    char* Bl = Al + 32768;
#pragma unroll
    for (int g = 0; g < 4; ++g) {
      const int flat = g * 512 + tid;
      const int row  = flat >> 3;                               // 0..255
      const int cb   = ((flat & 7) << 4) ^ ((row & 7) << 4);    // pre-swizzled src col
      gload_lds16((const char*)(A  + (size_t)(br + row) * K + k0) + cb,
                  Al + (g * 512 + wub) * 16);
      gload_lds16((const char*)(Bm + (size_t)(bc + row) * K + k0) + cb,
                  Bl + (g * 512 + wub) * 16);
    }
  };

  stage(0, 0);
  __syncthreads();

  for (int kt = 0; kt < nkt; ++kt) {
    const int b = kt & 1;
    const char* Ab = lds + b * 65536;
    const char* Bb = Ab + 32768;
    if (kt + 1 < nkt) stage(kt + 1, b ^ 1);    // front-loaded: lands by tile-end barrier
#pragma unroll
    for (int ks = 0; ks < 2; ++ks) {
      bf16x8 bfr[4];
#pragma unroll
      for (int n = 0; n < 4; ++n) {
        const int row = wn + n * 16 + l15;
        bfr[n] = *(const bf16x8*)(Bb + row * 128 + (((ks << 6) | lk16) ^ ((row & 7) << 4)));
      }
#pragma unroll
      for (int ph = 0; ph < 2; ++ph) {
        bf16x8 af[4];
#pragma unroll
        for (int mi = 0; mi < 4; ++mi) {
          const int row = wm + (ph * 4 + mi) * 16 + l15;
          af[mi] = *(const bf16x8*)(Ab + row * 128 + (((ks << 6) | lk16) ^ ((row & 7) << 4)));
        }
        __builtin_amdgcn_s_setprio(1);
#pragma unroll
        for (int mi = 0; mi < 4; ++mi)
#pragma unroll
          for (int n = 0; n < 4; ++n)
            acc[ph * 4 + mi][n] = __builtin_amdgcn_mfma_f32_16x16x32_bf16(
                af[mi], bfr[n], acc[ph * 4 + mi][n], 0, 0, 0);
        __builtin_amdgcn_s_setprio(0);
        if (ks * 2 + ph < 3) __builtin_amdgcn_s_barrier();   // phase sync, no vm drain
      }
    }
    __syncthreads();                            // buf handoff (vm drain: loads are old)
  }

  const int lr4 = ((lane >> 4) & 3) << 2;
  if (MODE == 0) {
    const bool isU = (bc < 1024);
    bf16* outp = isU ? out_u : out_v;
    const int obc = bc & 1023;
#pragma unroll
    for (int m = 0; m < 8; ++m) {
#pragma unroll
      for (int n = 0; n < 4; ++n) {
        const int colg = bc + wn + n * 16 + l15;
        const int ocol = obc + wn + n * 16 + l15;
        const float bv = bias[colg];
#pragma unroll
        for (int r = 0; r < 4; ++r) {
          const int row = br + wm + m * 16 + lr4 + r;
          float xv = acc[m][n][r] + bv;
          float s  = xv / (1.f + __expf(-xv));
          outp[(size_t)row * 1024 + ocol] = (bf16)s;
        }
      }
    }
  } else {
#pragma unroll
    for (int m = 0; m < 8; ++m) {
#pragma unroll
      for (int n = 0; n < 4; ++n) {
        const int col = bc + wn + n * 16 + l15;
        const float bv = bias[col];
#pragma unroll
        for (int r = 0; r < 4; ++r) {
          const int row = br + wm + m * 16 + lr4 + r;
          out_f[(size_t)row * N + col] = acc[m][n][r] + bv;
        }
      }
    }
  }
}

// ---------------- Toeplitz pass v5: register-shift window + prefetch -------------

#define VROW 130   // f32 row stride (128 + 2 pad)

template<int FUSE>
__global__ __launch_bounds__(256, 3)
void toep_pass(const bf16* __restrict__ in, const float* __restrict__ Tkf,
               const bf16* __restrict__ ufuse, bf16* __restrict__ out,
               int stride_j, int stride_row) {
  __shared__ float vbuf[64 * VROW];
  const int tid    = threadIdx.x;
  const int lane   = tid & 63;
  const int rowIdx = blockIdx.x >> 3;
  const int head   = blockIdx.x & 7;
  const size_t base = (size_t)(rowIdx >> 6) * 4194304
                    + (size_t)(rowIdx & 63) * stride_row + head * 128;

  const int i0 = (tid >> 6) << 4;
  const float* tg = Tkf + head * 127 * 128 + (lane << 1);

  // issue jb=0 T window early (latency overlaps staging+barrier)
  f32x2 t[31];
#pragma unroll
  for (int s = 0; s < 31; ++s)
    t[s] = *(const f32x2*)(tg + (i0 + 48 + s) * 128);

  // stage v row (64 j x 128 ch) bf16 -> f32
#pragma unroll
  for (int it = 0; it < 2; ++it) {
    int c  = it * 256 + tid;
    int j  = c >> 3;
    int cg = c & 7;
    const bf16* p = in + base + (size_t)j * stride_j + cg * 16;
    bf16x8 a0 = *(const bf16x8*)p;
    bf16x8 a1 = *(const bf16x8*)(p + 8);
    f32x4 f0 = {(float)a0[0], (float)a0[1], (float)a0[2], (float)a0[3]};
    f32x4 f1 = {(float)a0[4], (float)a0[5], (float)a0[6], (float)a0[7]};
    f32x4 f2 = {(float)a1[0], (float)a1[1], (float)a1[2], (float)a1[3]};
    f32x4 f3 = {(float)a1[4], (float)a1[5], (float)a1[6], (float)a1[7]};
    float* dst = &vbuf[j * VROW + cg * 16];
    *(f32x4*)(dst)      = f0;
    *(f32x4*)(dst + 4)  = f1;
    *(f32x4*)(dst + 8)  = f2;
    *(f32x4*)(dst + 12) = f3;
  }
  __syncthreads();

  f32x2 acc[16] = {};
#pragma unroll
  for (int jb = 0; jb < 4; ++jb) {
    f32x2 p16[16];
    if (jb < 3) {
#pragma unroll
      for (int s = 0; s < 16; ++s)
        p16[s] = *(const f32x2*)(tg + (i0 - 16 * (jb + 1) + 48 + s) * 128);
    }
#pragma unroll
    for (int jj = 0; jj < 16; ++jj) {
      f32x2 v2 = *(const f32x2*)&vbuf[(jb * 16 + jj) * VROW + (lane << 1)];
#pragma unroll
      for (int ii = 0; ii < 16; ++ii)
        acc[ii] = fma2(t[ii - jj + 15], v2, acc[ii]);
    }
    if (jb < 3) {
#pragma unroll
      for (int s = 30; s >= 16; --s) t[s] = t[s - 16];
#pragma unroll
      for (int s = 0; s < 16; ++s) t[s] = p16[s];
    }
  }

  const int d0 = lane << 1;
#pragma unroll
  for (int ii = 0; ii < 16; ++ii) {
    const size_t oidx = base + (size_t)(i0 + ii) * stride_j + d0;
    float a0 = acc[ii].x, a1 = acc[ii].y;
    if (FUSE) {
      bf16x2 uu = *(const bf16x2*)(ufuse + oidx);
      a0 *= (float)uu[0];
      a1 *= (float)uu[1];
    }
    bf16x2 o2 = {(bf16)a0, (bf16)a1};
    *(bf16x2*)(out + oidx) = o2;
  }
}

// ---------------- launch ----------------

extern "C" void kernel_launch(void* const* d_in, const int* in_sizes, int n_in,
                              void* d_out, int out_size, void* d_ws, size_t ws_size,
                              hipStream_t stream) {
  const float* x    = (const float*)d_in[0];
  const float* u_w  = (const float*)d_in[1];
  const float* u_b  = (const float*)d_in[2];
  const float* v_w  = (const float*)d_in[3];
  const float* v_b  = (const float*)d_in[4];
  const float* o_w  = (const float*)d_in[5];
  const float* o_b  = (const float*)d_in[6];
  const float* t1z  = (const float*)d_in[7];
  const float* t1pa = (const float*)d_in[8];
  const float* t1pb = (const float*)d_in[9];
  const float* t1na = (const float*)d_in[10];
  const float* t1nb = (const float*)d_in[11];
  const float* t2z  = (const float*)d_in[12];
  const float* t2pa = (const float*)d_in[13];
  const float* t2pb = (const float*)d_in[14];
  const float* t2na = (const float*)d_in[15];
  const float* t2nb = (const float*)d_in[16];

  char* ws = (char*)d_ws;
  size_t off = 0;
  auto alloc = [&](size_t bytes) {
    char* p = ws + off;
    off += (bytes + 255) & ~(size_t)255;
    return p;
  };
  bf16*  xb   = (bf16*)alloc(32768ull * 512 * 2);
  bf16*  wuv  = (bf16*)alloc(2048ull * 512 * 2);
  bf16*  owb  = (bf16*)alloc(512ull * 1024 * 2);
  float* buv  = (float*)alloc(2048ull * 4);
  float* Tkf1 = (float*)alloc(8ull * 127 * 128 * 4);
  float* Tkf2 = (float*)alloc(8ull * 127 * 128 * 4);
  bf16*  u    = (bf16*)alloc(32768ull * 1024 * 2);
  bf16*  v    = (bf16*)alloc(32768ull * 1024 * 2);
  bf16*  tmid = (bf16*)alloc(32768ull * 1024 * 2);
  bf16*  g    = v;   // v dead after toep1; reuse for gate output

  cast_f32_to_bf16<<<16384, 256, 0, stream>>>(x, xb, 16777216 / 4);
  cast_w3<<<1536, 256, 0, stream>>>(u_w, v_w, o_w, wuv, owb);
  concat_bias<<<4, 256, 0, stream>>>(u_b, v_b, buv);
  build_tkf<<<508, 256, 0, stream>>>(t1z, t1pa, t1pb, t1na, t1nb, Tkf1, 1.0f);
  build_tkf<<<508, 256, 0, stream>>>(t2z, t2pa, t2pb, t2na, t2nb, Tkf2, 2.0f);  // x2 folded

  // u,v = silu(x @ [Wu;Wv]^T + b)
  gemm8<0><<<1024, 512, 0, stream>>>(xb, wuv, buv, u, v, nullptr, 32768, 2048, 512);
  // W-axis mix (t1)
  toep_pass<0><<<4096, 256, 0, stream>>>(v, Tkf1, nullptr, tmid, 1024, 65536);
  // H-axis mix (t2), gate fused (x2 in Tkf2)
  toep_pass<1><<<4096, 256, 0, stream>>>(tmid, Tkf2, u, g, 65536, 1024);
  // out = g @ o_w^T + o_b
  gemm8<1><<<256, 512, 0, stream>>>(g, owb, o_b, nullptr, nullptr, (float*)d_out,
                                    32768, 512, 1024);
}

// Round 8
// 292.906 us; speedup vs baseline: 1.4267x; 1.0355x over previous
//
#include <hip/hip_runtime.h>
#include <hip/hip_bf16.h>
#include <hip/hip_fp16.h>

typedef __bf16 bf16;
typedef bf16 bf16x2 __attribute__((ext_vector_type(2)));
typedef bf16 bf16x4 __attribute__((ext_vector_type(4)));
typedef bf16 bf16x8 __attribute__((ext_vector_type(8)));
typedef float f32x2 __attribute__((ext_vector_type(2)));
typedef float f32x4 __attribute__((ext_vector_type(4)));

__device__ __forceinline__ void gload_lds16(const void* g, void* l) {
  __builtin_amdgcn_global_load_lds((__attribute__((address_space(1))) void*)g,
                                   (__attribute__((address_space(3))) void*)l,
                                   16, 0, 0);
}

__device__ __forceinline__ f32x2 fma2(f32x2 a, f32x2 b, f32x2 c) {
  return __builtin_elementwise_fma(a, b, c);   // -> v_pk_fma_f32
}

__device__ __forceinline__ float silu_f(float xv) {
  return xv * __builtin_amdgcn_rcpf(1.f + __expf(-xv));
}

// ---------------- prep kernels ----------------

__global__ void cast_f32_to_bf16(const float* __restrict__ in, bf16* __restrict__ out, int n4) {
  int i = blockIdx.x * blockDim.x + threadIdx.x;
  if (i >= n4) return;
  float4 v = ((const float4*)in)[i];
  bf16x4 o = {(bf16)v.x, (bf16)v.y, (bf16)v.z, (bf16)v.w};
  ((bf16x4*)out)[i] = o;
}

__global__ void cast_w3(const float* __restrict__ uw, const float* __restrict__ vw,
                        const float* __restrict__ ow,
                        bf16* __restrict__ wuv, bf16* __restrict__ owb) {
  int t = blockIdx.x * 256 + threadIdx.x;
  int r = t >> 17;
  int i = t & 131071;
  const float* src = (r == 0) ? uw : (r == 1) ? vw : ow;
  bf16* dst = (r == 2) ? owb : (wuv + (r == 1) * 524288);
  float4 v = ((const float4*)src)[i];
  bf16x4 o = {(bf16)v.x, (bf16)v.y, (bf16)v.z, (bf16)v.w};
  ((bf16x4*)dst)[i] = o;
}

__global__ void concat_bias(const float* __restrict__ ub, const float* __restrict__ vb,
                            float* __restrict__ buv) {
  int i = blockIdx.x * blockDim.x + threadIdx.x;
  if (i < 1024) { buv[i] = ub[i]; buv[1024 + i] = vb[i]; }
}

// Toeplitz table, f32: Tkf[h][lag+63][d], d = 0..127. L2-resident (520 KB).
__global__ void build_tkf(const float* __restrict__ zero, const float* __restrict__ pa,
                          const float* __restrict__ pb, const float* __restrict__ na,
                          const float* __restrict__ nb, float* __restrict__ Tkf,
                          float scale) {
  int idx = blockIdx.x * blockDim.x + threadIdx.x;
  if (idx >= 8 * 127 * 128) return;
  int d = idx & 127;
  int lagIdx = (idx >> 7) % 127;
  int h = idx / (128 * 127);
  int lag = lagIdx - 63;
  float val;
  if (lag == 0) {
    val = zero[h * 128 + d];
  } else {
    int k = lag > 0 ? lag : -lag;
    const float* A  = lag > 0 ? pa : na;
    const float* Bm = lag > 0 ? pb : nb;
    float pos_f = (float)(k - 1) * (15.0f / 62.0f);
    int lo = (int)floorf(pos_f);
    int hi = min(lo + 1, 15);
    float w = pos_f - (float)lo;
    float s = 0.f;
    for (int r = 0; r < 32; ++r) {
      float c = (1.f - w) * A[(h * 16 + lo) * 32 + r] + w * A[(h * 16 + hi) * 32 + r];
      s += c * Bm[(h * 32 + r) * 128 + d];
    }
    val = s * powf(0.999f, (float)k);
  }
  Tkf[idx] = val * scale;
}

// ------------- GEMM v3: 256x256 tile, BK=32, 8 waves, 3-buffer counted-vmcnt ------------
// T4 pipeline: stage(kt+2) issued each tile; wait vmcnt(4) (stage kt done, kt+1 in
// flight) -> never drains to 0 in main loop. One barrier/tile, no intra-tile barriers
// (waves free-run; T5 setprio around MFMA cluster). Buffer hazard: stage(kt+2) target
// last read at tile kt-1, separated by tile kt's barrier.
// MODE 0: bias+silu, bf16 out split u/v (stride 1024). MODE 1: bias, f32 out (stride N).

template<int MODE>
__global__ __launch_bounds__(512, 2)
void gemm8(const bf16* __restrict__ A, const bf16* __restrict__ Bm,
           const float* __restrict__ bias,
           bf16* __restrict__ out_u, bf16* __restrict__ out_v,
           float* __restrict__ out_f, int M, int N, int K) {
  __shared__ __align__(16) char lds[98304];   // 3 x (A 16KB | B 16KB)
  const int tid  = threadIdx.x;
  const int lane = tid & 63;
  const int l15  = lane & 15;
  const int lk16 = ((lane >> 4) & 3) << 4;     // frag k-offset in the 64B row
  const int w    = tid >> 6;
  const int wm   = (w >> 2) << 7;              // wave row base: 0 / 128
  const int wn   = (w & 3) << 6;               // wave col base: 0..192
  const int nbn  = N >> 8;
  const int cpx  = gridDim.x >> 3;
  const int swzb = (blockIdx.x & 7) * cpx + (blockIdx.x >> 3);
  const int br   = (swzb / nbn) << 8;
  const int bc   = (swzb % nbn) << 8;
  const int wub  = __builtin_amdgcn_readfirstlane(tid & 448);
  const int nkt  = K >> 5;

  f32x4 acc[8][4] = {};

  auto stage = [&](int kt, int b) {
    const int k0 = kt << 5;                    // BK=32 -> 64B rows
    char* Al = lds + b * 32768;
    char* Bl = Al + 16384;
#pragma unroll
    for (int g = 0; g < 2; ++g) {
      const int flat = g * 512 + tid;
      const int row  = flat >> 2;              // 0..255
      const int cb   = (flat & 3) << 4;        // 16B chunk in 64B row
      gload_lds16((const char*)(A  + (size_t)(br + row) * K + k0) + cb,
                  Al + (g * 512 + wub) * 16);
      gload_lds16((const char*)(Bm + (size_t)(bc + row) * K + k0) + cb,
                  Bl + (g * 512 + wub) * 16);
    }
  };

  stage(0, 0);
  stage(1, 1);

  int b = 0;
  for (int kt = 0; kt < nkt; ++kt) {
    if (kt + 1 < nkt) asm volatile("s_waitcnt vmcnt(4)" ::: "memory");
    else              asm volatile("s_waitcnt vmcnt(0)" ::: "memory");
    __builtin_amdgcn_s_barrier();
    __builtin_amdgcn_sched_barrier(0);
    if (kt + 2 < nkt) stage(kt + 2, b == 0 ? 2 : b - 1);   // (kt+2)%3

    const char* Ab = lds + b * 32768;
    const char* Bb = Ab + 16384;
    bf16x8 bfr[4];
#pragma unroll
    for (int n = 0; n < 4; ++n)
      bfr[n] = *(const bf16x8*)(Bb + (wn + n * 16 + l15) * 64 + lk16);
    __builtin_amdgcn_s_setprio(1);
#pragma unroll
    for (int m = 0; m < 8; ++m) {
      bf16x8 af = *(const bf16x8*)(Ab + (wm + m * 16 + l15) * 64 + lk16);
#pragma unroll
      for (int n = 0; n < 4; ++n)
        acc[m][n] = __builtin_amdgcn_mfma_f32_16x16x32_bf16(af, bfr[n], acc[m][n], 0, 0, 0);
    }
    __builtin_amdgcn_s_setprio(0);
    b = (b == 2) ? 0 : b + 1;
  }

  const int lr4 = ((lane >> 4) & 3) << 2;
  if (MODE == 0) {
    const bool isU = (bc < 1024);
    bf16* outp = isU ? out_u : out_v;
    const int obc = bc & 1023;
#pragma unroll
    for (int m = 0; m < 8; ++m) {
#pragma unroll
      for (int n = 0; n < 4; ++n) {
        const int colg = bc + wn + n * 16 + l15;
        const int ocol = obc + wn + n * 16 + l15;
        const float bv = bias[colg];
#pragma unroll
        for (int r = 0; r < 4; ++r) {
          const int row = br + wm + m * 16 + lr4 + r;
          outp[(size_t)row * 1024 + ocol] = (bf16)silu_f(acc[m][n][r] + bv);
        }
      }
    }
  } else {
#pragma unroll
    for (int m = 0; m < 8; ++m) {
#pragma unroll
      for (int n = 0; n < 4; ++n) {
        const int col = bc + wn + n * 16 + l15;
        const float bv = bias[col];
#pragma unroll
        for (int r = 0; r < 4; ++r) {
          const int row = br + wm + m * 16 + lr4 + r;
          out_f[(size_t)row * N + col] = acc[m][n][r] + bv;
        }
      }
    }
  }
}

// ---------------- Toeplitz pass v5: register-shift window + prefetch -------------

#define VROW 130   // f32 row stride (128 + 2 pad)

template<int FUSE>
__global__ __launch_bounds__(256, 3)
void toep_pass(const bf16* __restrict__ in, const float* __restrict__ Tkf,
               const bf16* __restrict__ ufuse, bf16* __restrict__ out,
               int stride_j, int stride_row) {
  __shared__ float vbuf[64 * VROW];
  const int tid    = threadIdx.x;
  const int lane   = tid & 63;
  const int rowIdx = blockIdx.x >> 3;
  const int head   = blockIdx.x & 7;
  const size_t base = (size_t)(rowIdx >> 6) * 4194304
                    + (size_t)(rowIdx & 63) * stride_row + head * 128;

  const int i0 = (tid >> 6) << 4;
  const float* tg = Tkf + head * 127 * 128 + (lane << 1);

  // issue jb=0 T window early (latency overlaps staging+barrier)
  f32x2 t[31];
#pragma unroll
  for (int s = 0; s < 31; ++s)
    t[s] = *(const f32x2*)(tg + (i0 + 48 + s) * 128);

  // stage v row (64 j x 128 ch) bf16 -> f32
#pragma unroll
  for (int it = 0; it < 2; ++it) {
    int c  = it * 256 + tid;
    int j  = c >> 3;
    int cg = c & 7;
    const bf16* p = in + base + (size_t)j * stride_j + cg * 16;
    bf16x8 a0 = *(const bf16x8*)p;
    bf16x8 a1 = *(const bf16x8*)(p + 8);
    f32x4 f0 = {(float)a0[0], (float)a0[1], (float)a0[2], (float)a0[3]};
    f32x4 f1 = {(float)a0[4], (float)a0[5], (float)a0[6], (float)a0[7]};
    f32x4 f2 = {(float)a1[0], (float)a1[1], (float)a1[2], (float)a1[3]};
    f32x4 f3 = {(float)a1[4], (float)a1[5], (float)a1[6], (float)a1[7]};
    float* dst = &vbuf[j * VROW + cg * 16];
    *(f32x4*)(dst)      = f0;
    *(f32x4*)(dst + 4)  = f1;
    *(f32x4*)(dst + 8)  = f2;
    *(f32x4*)(dst + 12) = f3;
  }
  __syncthreads();

  f32x2 acc[16] = {};
#pragma unroll
  for (int jb = 0; jb < 4; ++jb) {
    f32x2 p16[16];
    if (jb < 3) {
#pragma unroll
      for (int s = 0; s < 16; ++s)
        p16[s] = *(const f32x2*)(tg + (i0 - 16 * (jb + 1) + 48 + s) * 128);
    }
#pragma unroll
    for (int jj = 0; jj < 16; ++jj) {
      f32x2 v2 = *(const f32x2*)&vbuf[(jb * 16 + jj) * VROW + (lane << 1)];
#pragma unroll
      for (int ii = 0; ii < 16; ++ii)
        acc[ii] = fma2(t[ii - jj + 15], v2, acc[ii]);
    }
    if (jb < 3) {
#pragma unroll
      for (int s = 30; s >= 16; --s) t[s] = t[s - 16];
#pragma unroll
      for (int s = 0; s < 16; ++s) t[s] = p16[s];
    }
  }

  const int d0 = lane << 1;
#pragma unroll
  for (int ii = 0; ii < 16; ++ii) {
    const size_t oidx = base + (size_t)(i0 + ii) * stride_j + d0;
    float a0 = acc[ii].x, a1 = acc[ii].y;
    if (FUSE) {
      bf16x2 uu = *(const bf16x2*)(ufuse + oidx);
      a0 *= (float)uu[0];
      a1 *= (float)uu[1];
    }
    bf16x2 o2 = {(bf16)a0, (bf16)a1};
    *(bf16x2*)(out + oidx) = o2;
  }
}

// ---------------- launch ----------------

extern "C" void kernel_launch(void* const* d_in, const int* in_sizes, int n_in,
                              void* d_out, int out_size, void* d_ws, size_t ws_size,
                              hipStream_t stream) {
  const float* x    = (const float*)d_in[0];
  const float* u_w  = (const float*)d_in[1];
  const float* u_b  = (const float*)d_in[2];
  const float* v_w  = (const float*)d_in[3];
  const float* v_b  = (const float*)d_in[4];
  const float* o_w  = (const float*)d_in[5];
  const float* o_b  = (const float*)d_in[6];
  const float* t1z  = (const float*)d_in[7];
  const float* t1pa = (const float*)d_in[8];
  const float* t1pb = (const float*)d_in[9];
  const float* t1na = (const float*)d_in[10];
  const float* t1nb = (const float*)d_in[11];
  const float* t2z  = (const float*)d_in[12];
  const float* t2pa = (const float*)d_in[13];
  const float* t2pb = (const float*)d_in[14];
  const float* t2na = (const float*)d_in[15];
  const float* t2nb = (const float*)d_in[16];

  char* ws = (char*)d_ws;
  size_t off = 0;
  auto alloc = [&](size_t bytes) {
    char* p = ws + off;
    off += (bytes + 255) & ~(size_t)255;
    return p;
  };
  bf16*  xb   = (bf16*)alloc(32768ull * 512 * 2);
  bf16*  wuv  = (bf16*)alloc(2048ull * 512 * 2);
  bf16*  owb  = (bf16*)alloc(512ull * 1024 * 2);
  float* buv  = (float*)alloc(2048ull * 4);
  float* Tkf1 = (float*)alloc(8ull * 127 * 128 * 4);
  float* Tkf2 = (float*)alloc(8ull * 127 * 128 * 4);
  bf16*  u    = (bf16*)alloc(32768ull * 1024 * 2);
  bf16*  v    = (bf16*)alloc(32768ull * 1024 * 2);
  bf16*  tmid = (bf16*)alloc(32768ull * 1024 * 2);
  bf16*  g    = v;   // v dead after toep1; reuse for gate output

  cast_f32_to_bf16<<<16384, 256, 0, stream>>>(x, xb, 16777216 / 4);
  cast_w3<<<1536, 256, 0, stream>>>(u_w, v_w, o_w, wuv, owb);
  concat_bias<<<4, 256, 0, stream>>>(u_b, v_b, buv);
  build_tkf<<<508, 256, 0, stream>>>(t1z, t1pa, t1pb, t1na, t1nb, Tkf1, 1.0f);
  build_tkf<<<508, 256, 0, stream>>>(t2z, t2pa, t2pb, t2na, t2nb, Tkf2, 2.0f);  // x2 folded

  // u,v = silu(x @ [Wu;Wv]^T + b)
  gemm8<0><<<1024, 512, 0, stream>>>(xb, wuv, buv, u, v, nullptr, 32768, 2048, 512);
  // W-axis mix (t1)
  toep_pass<0><<<4096, 256, 0, stream>>>(v, Tkf1, nullptr, tmid, 1024, 65536);
  // H-axis mix (t2), gate fused (x2 in Tkf2)
  toep_pass<1><<<4096, 256, 0, stream>>>(tmid, Tkf2, u, g, 65536, 1024);
  // out = g @ o_w^T + o_b
  gemm8<1><<<256, 512, 0, stream>>>(g, owb, o_b, nullptr, nullptr, (float*)d_out,
                                    32768, 512, 1024);
}

// Round 9
// 286.523 us; speedup vs baseline: 1.4585x; 1.0223x over previous
//
#include <hip/hip_runtime.h>
#include <hip/hip_bf16.h>
#include <hip/hip_fp16.h>

typedef __bf16 bf16;
typedef bf16 bf16x2 __attribute__((ext_vector_type(2)));
typedef bf16 bf16x4 __attribute__((ext_vector_type(4)));
typedef bf16 bf16x8 __attribute__((ext_vector_type(8)));
typedef float f32x2 __attribute__((ext_vector_type(2)));
typedef float f32x4 __attribute__((ext_vector_type(4)));

__device__ __forceinline__ void gload_lds16(const void* g, void* l) {
  __builtin_amdgcn_global_load_lds((__attribute__((address_space(1))) void*)g,
                                   (__attribute__((address_space(3))) void*)l,
                                   16, 0, 0);
}

__device__ __forceinline__ f32x2 fma2(f32x2 a, f32x2 b, f32x2 c) {
  return __builtin_elementwise_fma(a, b, c);   // -> v_pk_fma_f32
}

__device__ __forceinline__ float silu_f(float xv) {
  return xv * __builtin_amdgcn_rcpf(1.f + __expf(-xv));
}

// ---------------- prep kernels ----------------

__global__ void cast_f32_to_bf16(const float* __restrict__ in, bf16* __restrict__ out, int n4) {
  int i = blockIdx.x * blockDim.x + threadIdx.x;
  if (i >= n4) return;
  float4 v = ((const float4*)in)[i];
  bf16x4 o = {(bf16)v.x, (bf16)v.y, (bf16)v.z, (bf16)v.w};
  ((bf16x4*)out)[i] = o;
}

__global__ void cast_w3(const float* __restrict__ uw, const float* __restrict__ vw,
                        const float* __restrict__ ow,
                        bf16* __restrict__ wuv, bf16* __restrict__ owb) {
  int t = blockIdx.x * 256 + threadIdx.x;
  int r = t >> 17;
  int i = t & 131071;
  const float* src = (r == 0) ? uw : (r == 1) ? vw : ow;
  bf16* dst = (r == 2) ? owb : (wuv + (r == 1) * 524288);
  float4 v = ((const float4*)src)[i];
  bf16x4 o = {(bf16)v.x, (bf16)v.y, (bf16)v.z, (bf16)v.w};
  ((bf16x4*)dst)[i] = o;
}

__global__ void concat_bias(const float* __restrict__ ub, const float* __restrict__ vb,
                            float* __restrict__ buv) {
  int i = blockIdx.x * blockDim.x + threadIdx.x;
  if (i < 1024) { buv[i] = ub[i]; buv[1024 + i] = vb[i]; }
}

// Toeplitz table, f32: Tkf[h][lag+63][d], d = 0..127. L2-resident (520 KB).
__global__ void build_tkf(const float* __restrict__ zero, const float* __restrict__ pa,
                          const float* __restrict__ pb, const float* __restrict__ na,
                          const float* __restrict__ nb, float* __restrict__ Tkf,
                          float scale) {
  int idx = blockIdx.x * blockDim.x + threadIdx.x;
  if (idx >= 8 * 127 * 128) return;
  int d = idx & 127;
  int lagIdx = (idx >> 7) % 127;
  int h = idx / (128 * 127);
  int lag = lagIdx - 63;
  float val;
  if (lag == 0) {
    val = zero[h * 128 + d];
  } else {
    int k = lag > 0 ? lag : -lag;
    const float* A  = lag > 0 ? pa : na;
    const float* Bm = lag > 0 ? pb : nb;
    float pos_f = (float)(k - 1) * (15.0f / 62.0f);
    int lo = (int)floorf(pos_f);
    int hi = min(lo + 1, 15);
    float w = pos_f - (float)lo;
    float s = 0.f;
    for (int r = 0; r < 32; ++r) {
      float c = (1.f - w) * A[(h * 16 + lo) * 32 + r] + w * A[(h * 16 + hi) * 32 + r];
      s += c * Bm[(h * 32 + r) * 128 + d];
    }
    val = s * powf(0.999f, (float)k);
  }
  Tkf[idx] = val * scale;
}

// ------- GEMM v4: 256x256, BK=64, 8 waves, 2-buffer, 0-conflict swizzle, 1 barrier/tile ----
// T2 XOR swizzle ((row&7)<<4 bytes within 128B rows): pre-swizzled global source +
// linear gload_lds dest + swizzled ds_read -> 0 bank conflicts (verified round 7).
// Pipeline: wait vmcnt(0) on stage(kt) issued ONE FULL TILE earlier (drain distance
// ~650cyc, not ~0 like m97); barrier; issue stage(kt+1) into buf^1 (safe: tile kt-1's
// reads of buf^1 returned before waves passed the barrier); compute tile kt with no
// intra-tile barriers (waves free-run; setprio around MFMA).
// MODE 0: bias+silu, bf16 out split u/v (stride 1024). MODE 1: bias, f32 out (stride N).

template<int MODE>
__global__ __launch_bounds__(512, 2)
void gemm8(const bf16* __restrict__ A, const bf16* __restrict__ Bm,
           const float* __restrict__ bias,
           bf16* __restrict__ out_u, bf16* __restrict__ out_v,
           float* __restrict__ out_f, int M, int N, int K) {
  __shared__ __align__(16) char lds[131072];   // 2 x (A 32KB | B 32KB)
  const int tid  = threadIdx.x;
  const int lane = tid & 63;
  const int l15  = lane & 15;
  const int lk16 = ((lane >> 4) & 3) << 4;     // frag k-offset (bytes) within 64B half-row
  const int w    = tid >> 6;
  const int wm   = (w >> 2) << 7;              // wave row base: 0 / 128
  const int wn   = (w & 3) << 6;               // wave col base: 0..192
  const int nbn  = N >> 8;
  const int cpx  = gridDim.x >> 3;
  const int swzb = (blockIdx.x & 7) * cpx + (blockIdx.x >> 3);
  const int br   = (swzb / nbn) << 8;
  const int bc   = (swzb % nbn) << 8;
  const int wub  = __builtin_amdgcn_readfirstlane(tid & 448);
  const int nkt  = K >> 6;

  f32x4 acc[8][4] = {};

  auto stage = [&](int kt, int b) {
    const int k0 = kt << 6;                    // BK=64 -> 128B rows
    char* Al = lds + b * 65536;
    char* Bl = Al + 32768;
#pragma unroll
    for (int g = 0; g < 4; ++g) {
      const int flat = g * 512 + tid;
      const int row  = flat >> 3;                               // 0..255
      const int cb   = ((flat & 7) << 4) ^ ((row & 7) << 4);    // pre-swizzled src col
      gload_lds16((const char*)(A  + (size_t)(br + row) * K + k0) + cb,
                  Al + (g * 512 + wub) * 16);
      gload_lds16((const char*)(Bm + (size_t)(bc + row) * K + k0) + cb,
                  Bl + (g * 512 + wub) * 16);
    }
  };

  stage(0, 0);

  for (int kt = 0; kt < nkt; ++kt) {
    const int b = kt & 1;
    asm volatile("s_waitcnt vmcnt(0)" ::: "memory");   // stage(kt): issued one tile ago
    __builtin_amdgcn_s_barrier();
    __builtin_amdgcn_sched_barrier(0);
    if (kt + 1 < nkt) stage(kt + 1, b ^ 1);            // overlaps this tile's compute

    const char* Ab = lds + b * 65536;
    const char* Bb = Ab + 32768;
#pragma unroll
    for (int ks = 0; ks < 2; ++ks) {
      bf16x8 bfr[4];
#pragma unroll
      for (int n = 0; n < 4; ++n) {
        const int row = wn + n * 16 + l15;
        bfr[n] = *(const bf16x8*)(Bb + row * 128 + (((ks << 6) | lk16) ^ ((row & 7) << 4)));
      }
      __builtin_amdgcn_s_setprio(1);
#pragma unroll
      for (int m = 0; m < 8; ++m) {
        const int row = wm + m * 16 + l15;
        bf16x8 af = *(const bf16x8*)(Ab + row * 128 + (((ks << 6) | lk16) ^ ((row & 7) << 4)));
#pragma unroll
        for (int n = 0; n < 4; ++n)
          acc[m][n] = __builtin_amdgcn_mfma_f32_16x16x32_bf16(af, bfr[n], acc[m][n], 0, 0, 0);
      }
      __builtin_amdgcn_s_setprio(0);
    }
  }

  const int lr4 = ((lane >> 4) & 3) << 2;
  if (MODE == 0) {
    const bool isU = (bc < 1024);
    bf16* outp = isU ? out_u : out_v;
    const int obc = bc & 1023;
#pragma unroll
    for (int m = 0; m < 8; ++m) {
#pragma unroll
      for (int n = 0; n < 4; ++n) {
        const int colg = bc + wn + n * 16 + l15;
        const int ocol = obc + wn + n * 16 + l15;
        const float bv = bias[colg];
#pragma unroll
        for (int r = 0; r < 4; ++r) {
          const int row = br + wm + m * 16 + lr4 + r;
          outp[(size_t)row * 1024 + ocol] = (bf16)silu_f(acc[m][n][r] + bv);
        }
      }
    }
  } else {
#pragma unroll
    for (int m = 0; m < 8; ++m) {
#pragma unroll
      for (int n = 0; n < 4; ++n) {
        const int col = bc + wn + n * 16 + l15;
        const float bv = bias[col];
#pragma unroll
        for (int r = 0; r < 4; ++r) {
          const int row = br + wm + m * 16 + lr4 + r;
          out_f[(size_t)row * N + col] = acc[m][n][r] + bv;
        }
      }
    }
  }
}

// ---------------- Toeplitz pass v5: register-shift window + prefetch -------------

#define VROW 130   // f32 row stride (128 + 2 pad)

template<int FUSE>
__global__ __launch_bounds__(256, 3)
void toep_pass(const bf16* __restrict__ in, const float* __restrict__ Tkf,
               const bf16* __restrict__ ufuse, bf16* __restrict__ out,
               int stride_j, int stride_row) {
  __shared__ float vbuf[64 * VROW];
  const int tid    = threadIdx.x;
  const int lane   = tid & 63;
  const int rowIdx = blockIdx.x >> 3;
  const int head   = blockIdx.x & 7;
  const size_t base = (size_t)(rowIdx >> 6) * 4194304
                    + (size_t)(rowIdx & 63) * stride_row + head * 128;

  const int i0 = (tid >> 6) << 4;
  const float* tg = Tkf + head * 127 * 128 + (lane << 1);

  // issue jb=0 T window early (latency overlaps staging+barrier)
  f32x2 t[31];
#pragma unroll
  for (int s = 0; s < 31; ++s)
    t[s] = *(const f32x2*)(tg + (i0 + 48 + s) * 128);

  // stage v row (64 j x 128 ch) bf16 -> f32
#pragma unroll
  for (int it = 0; it < 2; ++it) {
    int c  = it * 256 + tid;
    int j  = c >> 3;
    int cg = c & 7;
    const bf16* p = in + base + (size_t)j * stride_j + cg * 16;
    bf16x8 a0 = *(const bf16x8*)p;
    bf16x8 a1 = *(const bf16x8*)(p + 8);
    f32x4 f0 = {(float)a0[0], (float)a0[1], (float)a0[2], (float)a0[3]};
    f32x4 f1 = {(float)a0[4], (float)a0[5], (float)a0[6], (float)a0[7]};
    f32x4 f2 = {(float)a1[0], (float)a1[1], (float)a1[2], (float)a1[3]};
    f32x4 f3 = {(float)a1[4], (float)a1[5], (float)a1[6], (float)a1[7]};
    float* dst = &vbuf[j * VROW + cg * 16];
    *(f32x4*)(dst)      = f0;
    *(f32x4*)(dst + 4)  = f1;
    *(f32x4*)(dst + 8)  = f2;
    *(f32x4*)(dst + 12) = f3;
  }
  __syncthreads();

  f32x2 acc[16] = {};
#pragma unroll
  for (int jb = 0; jb < 4; ++jb) {
    f32x2 p16[16];
    if (jb < 3) {
#pragma unroll
      for (int s = 0; s < 16; ++s)
        p16[s] = *(const f32x2*)(tg + (i0 - 16 * (jb + 1) + 48 + s) * 128);
    }
#pragma unroll
    for (int jj = 0; jj < 16; ++jj) {
      f32x2 v2 = *(const f32x2*)&vbuf[(jb * 16 + jj) * VROW + (lane << 1)];
#pragma unroll
      for (int ii = 0; ii < 16; ++ii)
        acc[ii] = fma2(t[ii - jj + 15], v2, acc[ii]);
    }
    if (jb < 3) {
#pragma unroll
      for (int s = 30; s >= 16; --s) t[s] = t[s - 16];
#pragma unroll
      for (int s = 0; s < 16; ++s) t[s] = p16[s];
    }
  }

  const int d0 = lane << 1;
#pragma unroll
  for (int ii = 0; ii < 16; ++ii) {
    const size_t oidx = base + (size_t)(i0 + ii) * stride_j + d0;
    float a0 = acc[ii].x, a1 = acc[ii].y;
    if (FUSE) {
      bf16x2 uu = *(const bf16x2*)(ufuse + oidx);
      a0 *= (float)uu[0];
      a1 *= (float)uu[1];
    }
    bf16x2 o2 = {(bf16)a0, (bf16)a1};
    *(bf16x2*)(out + oidx) = o2;
  }
}

// ---------------- launch ----------------

extern "C" void kernel_launch(void* const* d_in, const int* in_sizes, int n_in,
                              void* d_out, int out_size, void* d_ws, size_t ws_size,
                              hipStream_t stream) {
  const float* x    = (const float*)d_in[0];
  const float* u_w  = (const float*)d_in[1];
  const float* u_b  = (const float*)d_in[2];
  const float* v_w  = (const float*)d_in[3];
  const float* v_b  = (const float*)d_in[4];
  const float* o_w  = (const float*)d_in[5];
  const float* o_b  = (const float*)d_in[6];
  const float* t1z  = (const float*)d_in[7];
  const float* t1pa = (const float*)d_in[8];
  const float* t1pb = (const float*)d_in[9];
  const float* t1na = (const float*)d_in[10];
  const float* t1nb = (const float*)d_in[11];
  const float* t2z  = (const float*)d_in[12];
  const float* t2pa = (const float*)d_in[13];
  const float* t2pb = (const float*)d_in[14];
  const float* t2na = (const float*)d_in[15];
  const float* t2nb = (const float*)d_in[16];

  char* ws = (char*)d_ws;
  size_t off = 0;
  auto alloc = [&](size_t bytes) {
    char* p = ws + off;
    off += (bytes + 255) & ~(size_t)255;
    return p;
  };
  bf16*  xb   = (bf16*)alloc(32768ull * 512 * 2);
  bf16*  wuv  = (bf16*)alloc(2048ull * 512 * 2);
  bf16*  owb  = (bf16*)alloc(512ull * 1024 * 2);
  float* buv  = (float*)alloc(2048ull * 4);
  float* Tkf1 = (float*)alloc(8ull * 127 * 128 * 4);
  float* Tkf2 = (float*)alloc(8ull * 127 * 128 * 4);
  bf16*  u    = (bf16*)alloc(32768ull * 1024 * 2);
  bf16*  v    = (bf16*)alloc(32768ull * 1024 * 2);
  bf16*  tmid = (bf16*)alloc(32768ull * 1024 * 2);
  bf16*  g    = v;   // v dead after toep1; reuse for gate output

  cast_f32_to_bf16<<<16384, 256, 0, stream>>>(x, xb, 16777216 / 4);
  cast_w3<<<1536, 256, 0, stream>>>(u_w, v_w, o_w, wuv, owb);
  concat_bias<<<4, 256, 0, stream>>>(u_b, v_b, buv);
  build_tkf<<<508, 256, 0, stream>>>(t1z, t1pa, t1pb, t1na, t1nb, Tkf1, 1.0f);
  build_tkf<<<508, 256, 0, stream>>>(t2z, t2pa, t2pb, t2na, t2nb, Tkf2, 2.0f);  // x2 folded

  // u,v = silu(x @ [Wu;Wv]^T + b)
  gemm8<0><<<1024, 512, 0, stream>>>(xb, wuv, buv, u, v, nullptr, 32768, 2048, 512);
  // W-axis mix (t1)
  toep_pass<0><<<4096, 256, 0, stream>>>(v, Tkf1, nullptr, tmid, 1024, 65536);
  // H-axis mix (t2), gate fused (x2 in Tkf2)
  toep_pass<1><<<4096, 256, 0, stream>>>(tmid, Tkf2, u, g, 65536, 1024);
  // out = g @ o_w^T + o_b
  gemm8<1><<<256, 512, 0, stream>>>(g, owb, o_b, nullptr, nullptr, (float*)d_out,
                                    32768, 512, 1024);
}